// Round 9
// baseline (117.849 us; speedup 1.0000x reference)
//
#include <hip/hip_runtime.h>
#include <math.h>

// B=16,H=14,W=14,D=512, L=32, HID=512, A=512.
// R21: R20 with the ctx-pass indexing bug fixed.
// R20 failed correctness (absmax 0.388): ctx used d0=tid*2 with 512 threads ->
// d0 up to 1022 overran the 512-col row, threads 256..511 wrote row-l0 sums
// into row l0+1 and row l0+1 sums into row l0+2 (another block's row: race).
// Fix: d = tid, one column per thread (the R18-proven form), scalar cstore.
// Everything else unchanged from R20:
//  - ONE kernel; per-b dataflow flags, fan-in 16 on 16 independent lines;
//    relaxed-only polling (no acquire -> no buffer_inv storm);
//  - BOUNDED spins (no wedge on aborted launches);
//  - epoch via per-block monotone g_blk[bx];
//  - cross-phase ws data via agent-scope relaxed atomics (LLC-coherent,
//    bypasses non-coherent per-XCD L2); u64/float2 where 8B-aligned;
//  - ordering: __syncthreads drains vmcnt before tid0's flag RMW; data
//    reaches LLC before the flag does; readers poll/load at LLC.
// Deadlock-safe: LDS 67.2KB -> 2 blocks/CU -> capacity 512 >= 256 blocks;
// every block publishes before its first spin.

typedef __attribute__((ext_vector_type(8))) short short8;
typedef __attribute__((ext_vector_type(4))) float f32x4;

__device__ unsigned g_flag1[16];   // .bss: zero at load, monotone forever
__device__ unsigned g_flag2[16];
__device__ unsigned g_blk[256];

#define SPIN_CAP 200000u

__device__ __forceinline__ float2 cload2(const float* p) {
    unsigned long long v = __hip_atomic_load((const unsigned long long*)p,
                                             __ATOMIC_RELAXED, __HIP_MEMORY_SCOPE_AGENT);
    union { unsigned long long u; float2 f; } c; c.u = v;
    return c.f;
}
__device__ __forceinline__ void cstore(float* p, float v) {
    __hip_atomic_store(p, v, __ATOMIC_RELAXED, __HIP_MEMORY_SCOPE_AGENT);
}
__device__ __forceinline__ unsigned frelax(unsigned* p) {
    return __hip_atomic_fetch_add(p, 1u, __ATOMIC_RELAXED, __HIP_MEMORY_SCOPE_AGENT);
}
__device__ __forceinline__ unsigned lrelax(const unsigned* p) {
    return __hip_atomic_load(p, __ATOMIC_RELAXED, __HIP_MEMORY_SCOPE_AGENT);
}

__device__ __forceinline__ unsigned f2bf_u(float x) {
    union { float f; unsigned u; } c; c.f = x;
    return (c.u + 0x7FFFu + ((c.u >> 16) & 1u)) >> 16;   // RNE, finite inputs
}
__device__ __forceinline__ unsigned pack2(float lo, float hi) {
    return f2bf_u(lo) | (f2bf_u(hi) << 16);
}
__device__ __forceinline__ uint4 pack8(const float4 a, const float4 b) {
    uint4 r;
    r.x = pack2(a.x, a.y); r.y = pack2(a.z, a.w);
    r.z = pack2(b.x, b.y); r.w = pack2(b.z, b.w);
    return r;
}
__device__ __forceinline__ float rdot4(const float4 f, const float4 g, const float4 w) {
    return fmaxf(f.x+g.x, 0.f)*w.x + fmaxf(f.y+g.y, 0.f)*w.y
         + fmaxf(f.z+g.z, 0.f)*w.z + fmaxf(f.w+g.w, 0.f)*w.w;
}
__device__ __forceinline__ float wave_sum(float v) {
    v += __shfl_down(v, 32); v += __shfl_down(v, 16); v += __shfl_down(v, 8);
    v += __shfl_down(v, 4);  v += __shfl_down(v, 2);  v += __shfl_down(v, 1);
    return v;   // lane 0 holds the sum
}

// ---- GEMM tile: C = A . B^T + bias[n] [* hmul] ; 512 thr, 8-wave split-K ----
template<int HMUL, int CLOADA, int CSTOREC>
__device__ __forceinline__ void gemm_body(char* smem,
    const float* __restrict__ Af, const float* __restrict__ Bf,
    const float* __restrict__ bias, const float* __restrict__ hmul,
    float* __restrict__ C)
{
    uint4* As = (uint4*)smem;               // 2048 slots (32KB)
    uint4* Bs = (uint4*)(smem + 32768);     // 2048 slots (32KB)
    float* red = (float*)smem;              // overlays As after sync
    const int tid = threadIdx.x, bid = blockIdx.x;

    const int m0 = (bid >> 4) * 32, n0 = (bid & 15) * 32;
    #pragma unroll
    for (int j = 0; j < 4; ++j) {
        const int S = tid + 512 * j;
        const int i = S >> 6, ln = S & 63;
        const int t = i & 1, s = i >> 1;
        const int row  = t * 16 + (ln & 15);
        const int col8 = s * 4 + (ln >> 4);
        const float* ap = Af + (size_t)(m0 + row) * 512 + col8 * 8;
        const float* bp = Bf + (size_t)(n0 + row) * 512 + col8 * 8;
        float4 av0, av1;
        if (CLOADA) {
            const float2 p0 = cload2(ap + 0), p1 = cload2(ap + 2);
            const float2 p2 = cload2(ap + 4), p3 = cload2(ap + 6);
            av0.x = p0.x; av0.y = p0.y; av0.z = p1.x; av0.w = p1.y;
            av1.x = p2.x; av1.y = p2.y; av1.z = p3.x; av1.w = p3.y;
        } else {
            av0 = *(const float4*)ap; av1 = *(const float4*)(ap + 4);
        }
        As[S] = pack8(av0, av1);
        Bs[S] = pack8(*(const float4*)bp, *(const float4*)(bp + 4));
    }
    __syncthreads();

    const int w = tid >> 6, ln = tid & 63;
    f32x4 acc[4];                            // fo = tm*2+tn
    #pragma unroll
    for (int fo = 0; fo < 4; ++fo) acc[fo] = (f32x4){0.f,0.f,0.f,0.f};
    #pragma unroll
    for (int sl = 0; sl < 2; ++sl) {
        const int s = 2 * w + sl;            // k-chunk 0..15
        const short8 a0 = *(const short8*)&As[(2*s+0)*64 + ln];
        const short8 a1 = *(const short8*)&As[(2*s+1)*64 + ln];
        const short8 b0 = *(const short8*)&Bs[(2*s+0)*64 + ln];
        const short8 b1 = *(const short8*)&Bs[(2*s+1)*64 + ln];
        acc[0] = __builtin_amdgcn_mfma_f32_16x16x32_bf16(a0, b0, acc[0], 0, 0, 0);
        acc[1] = __builtin_amdgcn_mfma_f32_16x16x32_bf16(a0, b1, acc[1], 0, 0, 0);
        acc[2] = __builtin_amdgcn_mfma_f32_16x16x32_bf16(a1, b0, acc[2], 0, 0, 0);
        acc[3] = __builtin_amdgcn_mfma_f32_16x16x32_bf16(a1, b1, acc[3], 0, 0, 0);
    }
    __syncthreads();                         // done reading As/Bs
    #pragma unroll
    for (int fo = 0; fo < 4; ++fo)
        #pragma unroll
        for (int r = 0; r < 4; ++r)
            red[w*1024 + fo*256 + r*64 + ln] = acc[fo][r];
    __syncthreads();
    #pragma unroll
    for (int jj = 0; jj < 2; ++jj) {
        const int o = tid + 512 * jj;        // 0..1023 outputs
        float v = 0.f;
        #pragma unroll
        for (int ww = 0; ww < 8; ++ww) v += red[ww*1024 + o];
        const int fo = o >> 8, r = (o >> 6) & 3, l2 = o & 63;
        // C/D layout: col = lane&15, row = (lane>>4)*4 + reg [m89-verified]
        const int m = m0 + (fo >> 1) * 16 + ((l2 >> 4) << 2) + r;
        const int n = n0 + (fo & 1) * 16 + (l2 & 15);
        v += bias[n];
        if (HMUL) v *= hmul[(size_t)m * 512 + n];
        if (CSTOREC) cstore(&C[(size_t)m * 512 + n], v);
        else         C[(size_t)m * 512 + n] = v;
    }
}

// ---- mid: (b XCD-affine, l-pair); hlin via cload2, ctx via cstore ----
__device__ __forceinline__ void mid_body(float* smrow, int b, int l0,
    const float* __restrict__ maps, const float* __restrict__ hlin,
    const float* __restrict__ W_rect, const float* __restrict__ b_rect,
    float* __restrict__ attn_out, float* __restrict__ ctx_out)
{
    const int tid = threadIdx.x;
    const int w = tid >> 6, lane = tid & 63;
    const int a_lo = lane * 4, a_hi = 256 + lane * 4;

    const float* h0p = hlin + ((size_t)b * 32 + l0) * 512;
    const float* h1p = h0p + 512;
    float4 g0_lo, g0_hi, g1_lo, g1_hi;
    { const float2 x = cload2(h0p+a_lo), y = cload2(h0p+a_lo+2);
      g0_lo.x = x.x; g0_lo.y = x.y; g0_lo.z = y.x; g0_lo.w = y.y; }
    { const float2 x = cload2(h0p+a_hi), y = cload2(h0p+a_hi+2);
      g0_hi.x = x.x; g0_hi.y = x.y; g0_hi.z = y.x; g0_hi.w = y.y; }
    { const float2 x = cload2(h1p+a_lo), y = cload2(h1p+a_lo+2);
      g1_lo.x = x.x; g1_lo.y = x.y; g1_lo.z = y.x; g1_lo.w = y.y; }
    { const float2 x = cload2(h1p+a_hi), y = cload2(h1p+a_hi+2);
      g1_hi.x = x.x; g1_hi.y = x.y; g1_hi.z = y.x; g1_hi.w = y.y; }
    const float4 w_lo  = *(const float4*)(W_rect + a_lo);
    const float4 w_hi  = *(const float4*)(W_rect + a_hi);
    const float br = b_rect[0];
    const float* mb = maps + (size_t)b * 196 * 512;

    // scores: wave w owns p === w (mod 8); direct float4 loads (HBM once -> L2)
    for (int p0 = w; p0 < 196; p0 += 8) {
        const float* fr = mb + (size_t)p0 * 512;
        const float4 fa = *(const float4*)(fr + a_lo);
        const float4 fb = *(const float4*)(fr + a_hi);
        float sA = rdot4(fa, g0_lo, w_lo) + rdot4(fb, g0_hi, w_hi);
        float sB = rdot4(fa, g1_lo, w_lo) + rdot4(fb, g1_hi, w_hi);
        sA = wave_sum(sA);
        sB = wave_sum(sB);
        if (lane == 0) { smrow[p0] = sA + br; smrow[208 + p0] = sB + br; }
    }
    __syncthreads();

    // softmax: wave 0 -> l0, wave 1 -> l0+1
    if (w < 2) {
        float v[4];
        #pragma unroll
        for (int i = 0; i < 4; ++i) {
            const int p = lane + 64 * i;
            v[i] = (p < 196) ? smrow[w * 208 + p] : -INFINITY;
        }
        float m = fmaxf(fmaxf(v[0], v[1]), fmaxf(v[2], v[3]));
        for (int off = 32; off > 0; off >>= 1) m = fmaxf(m, __shfl_down(m, off));
        m = __shfl(m, 0);
        float e[4], ssum = 0.f;
        #pragma unroll
        for (int i = 0; i < 4; ++i) {
            const int p = lane + 64 * i;
            e[i] = (p < 196) ? __expf(v[i] - m) : 0.f;
            ssum += e[i];
        }
        for (int off = 32; off > 0; off >>= 1) ssum += __shfl_down(ssum, off);
        ssum = __shfl(ssum, 0);
        const float inv = 1.f / ssum;
        float* ao = attn_out + ((size_t)b * 32 + l0 + w) * 196;
        #pragma unroll
        for (int i = 0; i < 4; ++i) {
            const int p = lane + 64 * i;
            if (p < 196) {
                const float at = e[i] * inv;
                smrow[w * 208 + p] = at;
                ao[p] = at;
            }
        }
    }
    __syncthreads();

    // ctx: thread owns col d = tid (512 thr / 512 cols); maps L2-hot after scores
    {
        const int d = tid;
        float a0=0.f,a1=0.f,a2=0.f,a3=0.f, c0=0.f,c1=0.f,c2=0.f,c3=0.f;
        for (int p = 0; p < 196; p += 4) {
            const float f0 = mb[(size_t)(p+0)*512 + d];
            const float f1 = mb[(size_t)(p+1)*512 + d];
            const float f2 = mb[(size_t)(p+2)*512 + d];
            const float f3 = mb[(size_t)(p+3)*512 + d];
            a0 += smrow[p+0]*f0; a1 += smrow[p+1]*f1;
            a2 += smrow[p+2]*f2; a3 += smrow[p+3]*f3;
            c0 += smrow[208+p+0]*f0; c1 += smrow[208+p+1]*f1;
            c2 += smrow[208+p+2]*f2; c3 += smrow[208+p+3]*f3;
        }
        float* cx = ctx_out + ((size_t)b * 32 + l0) * 512;
        cstore(cx + d,       (a0 + a1) + (a2 + a3));
        cstore(cx + 512 + d, (c0 + c1) + (c2 + c3));
    }
}

__global__ __launch_bounds__(512) void coatt_flow(
    const float* __restrict__ maps, const float* __restrict__ hiddens,
    const float* __restrict__ W_hidden, const float* __restrict__ b_hidden,
    const float* __restrict__ W_rect, const float* __restrict__ b_rect,
    const float* __restrict__ W_co, const float* __restrict__ b_co,
    float* __restrict__ out_co, float* __restrict__ attn_out,
    float* __restrict__ hlin_ws, float* __restrict__ ctx_ws)
{
    __shared__ __align__(16) char smem[65536];
    __shared__ __align__(16) float smrow[2 * 208];
    __shared__ unsigned s_r;

    const int tid = threadIdx.x, bx = blockIdx.x;
    const int b_gemm = bx >> 4;                             // m-tile batch
    const int b_mid  = ((bx & 7) << 1) | ((bx >> 3) & 1);   // XCD-affine batch
    const int l0     = (bx >> 4) * 2;

    if (tid == 0)
        s_r = frelax(&g_blk[bx]);      // replay epoch (only block bx touches it)
    __syncthreads();
    const unsigned tgt = 16u * (s_r + 1u);

    // ---- phase 1: gemm1 tile -> hlin (coherent stores) ----
    gemm_body<0, 0, 1>(smem, hiddens, W_hidden, b_hidden,
                       (const float*)nullptr, hlin_ws);
    __syncthreads();                   // drains vmcnt: hlin stores at LLC
    if (tid == 0) {
        frelax(&g_flag1[b_gemm]);      // publish before first spin (no deadlock)
        unsigned it = 0;
        while (lrelax(&g_flag1[b_mid]) < tgt && ++it < SPIN_CAP)
            __builtin_amdgcn_s_sleep(8);
    }
    __syncthreads();

    // ---- phase 2: mid -> attn_out (plain) + ctx (coherent stores) ----
    mid_body(smrow, b_mid, l0, maps, hlin_ws, W_rect, b_rect, attn_out, ctx_ws);
    __syncthreads();                   // drains vmcnt: ctx stores at LLC
    if (tid == 0) {
        frelax(&g_flag2[b_mid]);
        unsigned it = 0;
        while (lrelax(&g_flag2[b_gemm]) < tgt && ++it < SPIN_CAP)
            __builtin_amdgcn_s_sleep(8);
    }
    __syncthreads();

    // ---- phase 3: gemm2 tile (ctx via coherent loads) -> out (plain) ----
    gemm_body<1, 1, 0>(smem, ctx_ws, W_co, b_co, hiddens, out_co);
}

extern "C" void kernel_launch(void* const* d_in, const int* in_sizes, int n_in,
                              void* d_out, int out_size, void* d_ws, size_t ws_size,
                              hipStream_t stream)
{
    const float* maps     = (const float*)d_in[0];
    const float* hiddens  = (const float*)d_in[1];
    const float* W_hidden = (const float*)d_in[2];
    const float* b_hidden = (const float*)d_in[3];
    const float* W_rect   = (const float*)d_in[4];
    const float* b_rect   = (const float*)d_in[5];
    const float* W_co     = (const float*)d_in[6];
    const float* b_co     = (const float*)d_in[7];

    float* out_co   = (float*)d_out;                    // (512,512)
    float* out_attn = out_co + (size_t)512 * 512;       // (512,196)
    float* hlin     = (float*)d_ws;                     // (512,512) fp32
    float* ctx      = hlin + (size_t)512 * 512;         // (512,512) fp32

    hipLaunchKernelGGL(coatt_flow, dim3(256), dim3(512), 0, stream,
                       maps, hiddens, W_hidden, b_hidden, W_rect, b_rect,
                       W_co, b_co, out_co, out_attn, hlin, ctx);
}